// Round 1
// baseline (1616.304 us; speedup 1.0000x reference)
//
#include <hip/hip_runtime.h>
#include <hip/hip_bf16.h>
#include <stdint.h>

#define B_ROWS 4096
#define HD 1024
#define IN_DIM 784
#define IN_PAD 800
#define T_TICKS 32

typedef float f32x4 __attribute__((ext_vector_type(4)));
typedef short short8 __attribute__((ext_vector_type(8)));
typedef __hip_bfloat16 bf16;

__device__ __forceinline__ float b2f(short s) {
  unsigned u = ((unsigned)(unsigned short)s) << 16;
  float f; __builtin_memcpy(&f, &u, 4); return f;
}

__device__ __forceinline__ float softplus_f(float x) {
  if (x > 20.f) return x;
  return log1pf(expf(x));
}

__device__ __forceinline__ void gload_lds16(const void* g, void* l) {
  __builtin_amdgcn_global_load_lds(
      (const __attribute__((address_space(1))) uint32_t*)g,
      (__attribute__((address_space(3))) uint32_t*)l, 16, 0, 0);
}

// ---------- convert f32 -> bf16 with optional zero-pad of inner dim ----------
__global__ __launch_bounds__(256) void conv_pad_kernel(
    const float* __restrict__ src, bf16* __restrict__ dst,
    int rows, int scols, int dcols) {
  int idx = blockIdx.x * 256 + threadIdx.x;
  int total = rows * dcols;
  if (idx >= total) return;
  int r = idx / dcols, c = idx - r * dcols;
  float v = (c < scols) ? src[(size_t)r * scols + c] : 0.f;
  dst[idx] = __float2bfloat16(v);
}

// ---------- GEMM C = A * B^T  (A: M x K row-major bf16, B: N x K row-major bf16) ----
// 128x128 tile, BK=32, 256 threads (4 waves of 64x64), global_load_lds staging.
// MODE 0: outF[row][col] = acc + bias[col]              (x_proj)
// MODE 1: outH[row][col] = bf16(tanh(acc + xproj + bias))  (tick)
template<int KDIM, int MODE>
__global__ __launch_bounds__(256) void gemm_bt(
    const bf16* __restrict__ A, int ldaB,
    const bf16* __restrict__ Bw, int ldbB,
    const float* __restrict__ bias,
    const float* __restrict__ xproj,
    float* __restrict__ outF, bf16* __restrict__ outH)
{
  __shared__ bf16 lA[128 * 32];
  __shared__ bf16 lB[128 * 32];
  const int tid = threadIdx.x;
  const int lane = tid & 63, w = tid >> 6;
  const int wr = w & 1, wc = w >> 1;
  const int bm0 = blockIdx.x * 128, bn0 = blockIdx.y * 128;
  const int r = lane & 15, q = lane >> 4;

  f32x4 acc[4][4] = {};

  const char* Ab = (const char*)A + (size_t)bm0 * ldaB;
  const char* Bb = (const char*)Bw + (size_t)bn0 * ldbB;

  for (int kt = 0; kt < KDIM / 32; ++kt) {
#pragma unroll
    for (int l = 0; l < 2; ++l) {
      int ci = (w * 2 + l) * 64 + lane;   // 0..511 chunk of 16B
      int row = ci >> 2, kp = ci & 3;
      const char* srcA = Ab + (size_t)row * ldaB + kt * 64 + kp * 16;
      const char* srcB = Bb + (size_t)row * ldbB + kt * 64 + kp * 16;
      gload_lds16(srcA, &lA[(w * 2 + l) * 512]);
      gload_lds16(srcB, &lB[(w * 2 + l) * 512]);
    }
    __syncthreads();
    short8 af[4], bfr[4];
#pragma unroll
    for (int m = 0; m < 4; ++m)
      af[m] = *(const short8*)&lA[(wr * 64 + m * 16 + r) * 32 + q * 8];
#pragma unroll
    for (int n = 0; n < 4; ++n)
      bfr[n] = *(const short8*)&lB[(wc * 64 + n * 16 + r) * 32 + q * 8];
#pragma unroll
    for (int m = 0; m < 4; ++m)
#pragma unroll
      for (int n = 0; n < 4; ++n)
        acc[m][n] = __builtin_amdgcn_mfma_f32_16x16x32_bf16(af[m], bfr[n], acc[m][n], 0, 0, 0);
    __syncthreads();
  }

#pragma unroll
  for (int m = 0; m < 4; ++m) {
#pragma unroll
    for (int n = 0; n < 4; ++n) {
      int col = bn0 + wc * 64 + n * 16 + r;
#pragma unroll
      for (int i = 0; i < 4; ++i) {
        int row = bm0 + wr * 64 + m * 16 + q * 4 + i;
        float v = acc[m][n][i];
        if (MODE == 0) {
          outF[(size_t)row * HD + col] = v + bias[col];
        } else {
          float val = tanhf(v + xproj[(size_t)row * HD + col] + bias[col]);
          outH[(size_t)row * HD + col] = __float2bfloat16(val);
        }
      }
    }
  }
}

// ---------- fe head: one wave per row, 5 dot products of length 1024 ----------
__global__ __launch_bounds__(256) void fe_head(
    const bf16* __restrict__ h, const float* __restrict__ feW,
    const float* __restrict__ feB, const float* __restrict__ eps,
    float* __restrict__ out, int t)
{
  int wid = threadIdx.x >> 6, lane = threadIdx.x & 63;
  int b = blockIdx.x * 4 + wid;
  const bf16* hr = h + (size_t)b * HD + lane * 16;
  short8 hv0 = *(const short8*)hr;
  short8 hv1 = *(const short8*)(hr + 8);
  float hvf[16];
#pragma unroll
  for (int e = 0; e < 8; ++e) { hvf[e] = b2f(hv0[e]); hvf[8 + e] = b2f(hv1[e]); }

  float a0 = 0, a1 = 0, a2 = 0, a3 = 0, a4 = 0;
  int col0 = lane * 16;
#pragma unroll
  for (int e = 0; e < 16; ++e) {
    float hv = hvf[e];
    int col = col0 + e;
    a0 += hv * feW[0 * HD + col];
    a1 += hv * feW[1 * HD + col];
    a2 += hv * feW[2 * HD + col];
    a3 += hv * feW[3 * HD + col];
    a4 += hv * feW[4 * HD + col];
  }
#pragma unroll
  for (int off = 32; off >= 1; off >>= 1) {
    a0 += __shfl_xor(a0, off);
    a1 += __shfl_xor(a1, off);
    a2 += __shfl_xor(a2, off);
    a3 += __shfl_xor(a3, off);
    a4 += __shfl_xor(a4, off);
  }
  if (lane == 0) {
    float mu0 = a0 + feB[0], mu1 = a1 + feB[1];
    float L00 = softplus_f(a2 + feB[2]);
    float L10 = a3 + feB[3];
    float L11 = softplus_f(a4 + feB[4]);
    const float* ep = eps + ((size_t)t * B_ROWS + b) * 2;
    float e0 = ep[0], e1 = ep[1];
    float z0 = mu0 + L00 * e0;
    float z1 = mu1 + L10 * e0 + L11 * e1;

    float* zs0 = out;
    float* zs1 = out + (size_t)B_ROWS * 2 * T_TICKS;
    float* Ls  = out + (size_t)2 * B_ROWS * 2 * T_TICKS;
    size_t zb = (size_t)b * 2 * T_TICKS + t;
    zs0[zb] = z0; zs0[zb + T_TICKS] = z1;
    zs1[zb] = z0; zs1[zb + T_TICKS] = z1;
    size_t lb = (size_t)b * 4 * T_TICKS + t;
    Ls[lb] = L00;
    Ls[lb + T_TICKS] = 0.f;
    Ls[lb + 2 * T_TICKS] = L10;
    Ls[lb + 3 * T_TICKS] = L11;
  }
}

extern "C" void kernel_launch(void* const* d_in, const int* in_sizes, int n_in,
                              void* d_out, int out_size, void* d_ws, size_t ws_size,
                              hipStream_t stream) {
  const float* x    = (const float*)d_in[0];
  const float* hx   = (const float*)d_in[1];
  const float* eps  = (const float*)d_in[2];
  const float* W_ih = (const float*)d_in[3];
  const float* b_ih = (const float*)d_in[4];
  const float* W_hh = (const float*)d_in[5];
  const float* b_hh = (const float*)d_in[6];
  const float* fe_W = (const float*)d_in[7];
  const float* fe_b = (const float*)d_in[8];
  float* out = (float*)d_out;

  char* ws = (char*)d_ws;
  bf16* x_bf   = (bf16*)ws;  ws += (size_t)B_ROWS * IN_PAD * 2;
  bf16* wih_bf = (bf16*)ws;  ws += (size_t)HD * IN_PAD * 2;
  bf16* whh_bf = (bf16*)ws;  ws += (size_t)HD * HD * 2;
  float* xproj = (float*)ws; ws += (size_t)B_ROWS * HD * 4;
  bf16* hA = (bf16*)ws;      ws += (size_t)B_ROWS * HD * 2;
  bf16* hB = (bf16*)ws;      ws += (size_t)B_ROWS * HD * 2;

  conv_pad_kernel<<<(B_ROWS * IN_PAD + 255) / 256, 256, 0, stream>>>(x, x_bf, B_ROWS, IN_DIM, IN_PAD);
  conv_pad_kernel<<<(HD * IN_PAD + 255) / 256, 256, 0, stream>>>(W_ih, wih_bf, HD, IN_DIM, IN_PAD);
  conv_pad_kernel<<<(HD * HD + 255) / 256, 256, 0, stream>>>(W_hh, whh_bf, HD, HD, HD);
  conv_pad_kernel<<<(B_ROWS * HD + 255) / 256, 256, 0, stream>>>(hx, hA, B_ROWS, HD, HD);

  dim3 ggrid(B_ROWS / 128, HD / 128);
  gemm_bt<IN_PAD, 0><<<ggrid, 256, 0, stream>>>(x_bf, IN_PAD * 2, wih_bf, IN_PAD * 2,
                                                b_ih, nullptr, xproj, nullptr);
  for (int t = 0; t < T_TICKS; ++t) {
    const bf16* hin = (t & 1) ? hB : hA;
    bf16* hout      = (t & 1) ? hA : hB;
    gemm_bt<HD, 1><<<ggrid, 256, 0, stream>>>(hin, HD * 2, whh_bf, HD * 2,
                                              b_hh, xproj, nullptr, hout);
    fe_head<<<B_ROWS / 4, 256, 0, stream>>>(hout, fe_W, fe_b, eps, out, t);
  }
}

// Round 2
// 987.171 us; speedup vs baseline: 1.6373x; 1.6373x over previous
//
#include <hip/hip_runtime.h>
#include <hip/hip_bf16.h>
#include <stdint.h>

#define B_ROWS 4096
#define HD 1024
#define IN_DIM 784
#define IN_PAD 832
#define T_TICKS 32

typedef float f32x4 __attribute__((ext_vector_type(4)));
typedef short short8 __attribute__((ext_vector_type(8)));
typedef __hip_bfloat16 bf16;

__device__ __forceinline__ float b2f(short s) {
  unsigned u = ((unsigned)(unsigned short)s) << 16;
  float f; __builtin_memcpy(&f, &u, 4); return f;
}

__device__ __forceinline__ float softplus_f(float x) {
  if (x > 20.f) return x;
  return log1pf(expf(x));
}

__device__ __forceinline__ float tanh_fast(float x) {
  x = fminf(fmaxf(x, -15.f), 15.f);
  float e = __expf(2.f * x);
  return (e - 1.f) / (e + 1.f);
}

__device__ __forceinline__ void gload_lds16(const void* g, void* l) {
  __builtin_amdgcn_global_load_lds(
      (const __attribute__((address_space(1))) uint32_t*)g,
      (__attribute__((address_space(3))) uint32_t*)l, 16, 0, 0);
}

// ---------- convert f32 -> bf16 with optional zero-pad of inner dim ----------
__global__ __launch_bounds__(256) void conv_pad_kernel(
    const float* __restrict__ src, bf16* __restrict__ dst,
    int rows, int scols, int dcols) {
  int idx = blockIdx.x * 256 + threadIdx.x;
  int total = rows * dcols;
  if (idx >= total) return;
  int r = idx / dcols, c = idx - r * dcols;
  float v = (c < scols) ? src[(size_t)r * scols + c] : 0.f;
  dst[idx] = __float2bfloat16(v);
}

// ---------- GEMM C = A * B^T ----------
// BM=64, BN=128, BK=64, 256 threads (4 waves 2x2, wave tile 32x64).
// Double-buffered LDS, 2-phase prefetch, XOR-swizzled LDS (pre-swizzled global src).
// MODE 0: outF[row][col] = acc + bias1[col] + bias2[col]          (x_proj + both biases)
// MODE 1: outH[row][col] = bf16(tanh(acc + xproj[row][col]))       (tick)
template<int KDIM, int MODE>
__global__ __launch_bounds__(256) void gemm_bt(
    const bf16* __restrict__ A, int ldaB,
    const bf16* __restrict__ Bw, int ldbB,
    const float* __restrict__ bias1, const float* __restrict__ bias2,
    const float* __restrict__ xproj,
    float* __restrict__ outF, bf16* __restrict__ outH)
{
  __shared__ bf16 lA[2][64 * 64];    // 2 x 8KB
  __shared__ bf16 lB[2][128 * 64];   // 2 x 16KB
  const int tid = threadIdx.x;
  const int lane = tid & 63, w = tid >> 6;
  const int wm = w & 1, wn = w >> 1;
  const int l3 = lane >> 3, l7 = lane & 7;
  const int gcol = l7 ^ l3;               // inverse-swizzled source chunk (128B rows, 8x16B)
  const int r = lane & 15, q = lane >> 4;
  const int r7 = r & 7;

  // XCD-chunked swizzle: 512 blocks, 8 XCDs, 64 blocks/XCD; each XCD gets
  // mx in [xcd*8, xcd*8+8) x all 8 ny -> A slice 1MB + W 2MB L2-resident.
  int bid = blockIdx.x;
  int xcd = bid & 7, loc = bid >> 3;
  int mx = xcd * 8 + (loc & 7), ny = loc >> 3;
  const int bm0 = mx * 64, bn0 = ny * 128;

  f32x4 acc[2][4] = {};

  const char* Asrc = (const char*)A + (size_t)(bm0 + l3) * ldaB + gcol * 16;
  const char* Bsrc = (const char*)Bw + (size_t)(bn0 + l3) * ldbB + gcol * 16;
  char* lAb0 = (char*)&lA[0][0];
  char* lBb0 = (char*)&lB[0][0];

  const int NK = KDIM / 64;

#define STAGE(buf, kt)                                                         \
  {                                                                            \
    const char* Ak = Asrc + (kt) * 128;                                        \
    const char* Bk = Bsrc + (kt) * 128;                                        \
    _Pragma("unroll") for (int j = 0; j < 2; ++j) {                            \
      int iA = w * 2 + j;                                                      \
      gload_lds16(Ak + (size_t)iA * 8 * ldaB, lAb0 + (buf) * 8192 + iA * 1024);\
    }                                                                          \
    _Pragma("unroll") for (int j = 0; j < 4; ++j) {                            \
      int iB = w * 4 + j;                                                      \
      gload_lds16(Bk + (size_t)iB * 8 * ldbB, lBb0 + (buf) * 16384 + iB * 1024);\
    }                                                                          \
  }

  STAGE(0, 0);
  __syncthreads();
  int cur = 0;

  for (int kt = 0; kt < NK; ++kt) {
    if (kt + 1 < NK) STAGE(cur ^ 1, kt + 1);

    const char* lAb = lAb0 + cur * 8192;
    const char* lBb = lBb0 + cur * 16384;
    short8 af[2][2], bfr[2][4];
#pragma unroll
    for (int ks = 0; ks < 2; ++ks) {
      int cc = ks * 4 + q;
      int sw = (cc ^ r7) << 4;
#pragma unroll
      for (int m = 0; m < 2; ++m) {
        int row = wm * 32 + m * 16 + r;
        af[ks][m] = *(const short8*)(lAb + row * 128 + sw);
      }
#pragma unroll
      for (int n = 0; n < 4; ++n) {
        int row = wn * 64 + n * 16 + r;
        bfr[ks][n] = *(const short8*)(lBb + row * 128 + sw);
      }
    }
#pragma unroll
    for (int ks = 0; ks < 2; ++ks)
#pragma unroll
      for (int m = 0; m < 2; ++m)
#pragma unroll
        for (int n = 0; n < 4; ++n)
          acc[m][n] = __builtin_amdgcn_mfma_f32_16x16x32_bf16(af[ks][m], bfr[ks][n], acc[m][n], 0, 0, 0);

    __syncthreads();
    cur ^= 1;
  }
#undef STAGE

#pragma unroll
  for (int m = 0; m < 2; ++m) {
#pragma unroll
    for (int n = 0; n < 4; ++n) {
      int col = bn0 + wn * 64 + n * 16 + r;
#pragma unroll
      for (int i = 0; i < 4; ++i) {
        int row = bm0 + wm * 32 + m * 16 + q * 4 + i;
        float v = acc[m][n][i];
        if (MODE == 0) {
          outF[(size_t)row * HD + col] = v + bias1[col] + bias2[col];
        } else {
          float val = tanh_fast(v + xproj[(size_t)row * HD + col]);
          outH[(size_t)row * HD + col] = __float2bfloat16(val);
        }
      }
    }
  }
}

// ---------- fe head: one wave per row, 5 dot products of length 1024 ----------
__global__ __launch_bounds__(256) void fe_head(
    const bf16* __restrict__ h, const float* __restrict__ feW,
    const float* __restrict__ feB, const float* __restrict__ eps,
    float* __restrict__ out, int t)
{
  int wid = threadIdx.x >> 6, lane = threadIdx.x & 63;
  int b = blockIdx.x * 4 + wid;
  const bf16* hr = h + (size_t)b * HD + lane * 16;
  short8 hv0 = *(const short8*)hr;
  short8 hv1 = *(const short8*)(hr + 8);
  float hvf[16];
#pragma unroll
  for (int e = 0; e < 8; ++e) { hvf[e] = b2f(hv0[e]); hvf[8 + e] = b2f(hv1[e]); }

  float a0 = 0, a1 = 0, a2 = 0, a3 = 0, a4 = 0;
  int col0 = lane * 16;
#pragma unroll
  for (int e = 0; e < 16; ++e) {
    float hv = hvf[e];
    int col = col0 + e;
    a0 += hv * feW[0 * HD + col];
    a1 += hv * feW[1 * HD + col];
    a2 += hv * feW[2 * HD + col];
    a3 += hv * feW[3 * HD + col];
    a4 += hv * feW[4 * HD + col];
  }
#pragma unroll
  for (int off = 32; off >= 1; off >>= 1) {
    a0 += __shfl_xor(a0, off);
    a1 += __shfl_xor(a1, off);
    a2 += __shfl_xor(a2, off);
    a3 += __shfl_xor(a3, off);
    a4 += __shfl_xor(a4, off);
  }
  if (lane == 0) {
    float mu0 = a0 + feB[0], mu1 = a1 + feB[1];
    float L00 = softplus_f(a2 + feB[2]);
    float L10 = a3 + feB[3];
    float L11 = softplus_f(a4 + feB[4]);
    const float* ep = eps + ((size_t)t * B_ROWS + b) * 2;
    float e0 = ep[0], e1 = ep[1];
    float z0 = mu0 + L00 * e0;
    float z1 = mu1 + L10 * e0 + L11 * e1;

    float* zs0 = out;
    float* zs1 = out + (size_t)B_ROWS * 2 * T_TICKS;
    float* Ls  = out + (size_t)2 * B_ROWS * 2 * T_TICKS;
    size_t zb = (size_t)b * 2 * T_TICKS + t;
    zs0[zb] = z0; zs0[zb + T_TICKS] = z1;
    zs1[zb] = z0; zs1[zb + T_TICKS] = z1;
    size_t lb = (size_t)b * 4 * T_TICKS + t;
    Ls[lb] = L00;
    Ls[lb + T_TICKS] = 0.f;
    Ls[lb + 2 * T_TICKS] = L10;
    Ls[lb + 3 * T_TICKS] = L11;
  }
}

extern "C" void kernel_launch(void* const* d_in, const int* in_sizes, int n_in,
                              void* d_out, int out_size, void* d_ws, size_t ws_size,
                              hipStream_t stream) {
  const float* x    = (const float*)d_in[0];
  const float* hx   = (const float*)d_in[1];
  const float* eps  = (const float*)d_in[2];
  const float* W_ih = (const float*)d_in[3];
  const float* b_ih = (const float*)d_in[4];
  const float* W_hh = (const float*)d_in[5];
  const float* b_hh = (const float*)d_in[6];
  const float* fe_W = (const float*)d_in[7];
  const float* fe_b = (const float*)d_in[8];
  float* out = (float*)d_out;

  char* ws = (char*)d_ws;
  bf16* x_bf   = (bf16*)ws;  ws += (size_t)B_ROWS * IN_PAD * 2;
  bf16* wih_bf = (bf16*)ws;  ws += (size_t)HD * IN_PAD * 2;
  bf16* whh_bf = (bf16*)ws;  ws += (size_t)HD * HD * 2;
  float* xproj = (float*)ws; ws += (size_t)B_ROWS * HD * 4;
  bf16* hA = (bf16*)ws;      ws += (size_t)B_ROWS * HD * 2;
  bf16* hB = (bf16*)ws;      ws += (size_t)B_ROWS * HD * 2;

  conv_pad_kernel<<<(B_ROWS * IN_PAD + 255) / 256, 256, 0, stream>>>(x, x_bf, B_ROWS, IN_DIM, IN_PAD);
  conv_pad_kernel<<<(HD * IN_PAD + 255) / 256, 256, 0, stream>>>(W_ih, wih_bf, HD, IN_DIM, IN_PAD);
  conv_pad_kernel<<<(HD * HD + 255) / 256, 256, 0, stream>>>(W_hh, whh_bf, HD, HD, HD);
  conv_pad_kernel<<<(B_ROWS * HD + 255) / 256, 256, 0, stream>>>(hx, hA, B_ROWS, HD, HD);

  // grid: 64 M-tiles x 8 N-tiles = 512 blocks (1D, XCD-swizzled inside)
  gemm_bt<IN_PAD, 0><<<512, 256, 0, stream>>>(x_bf, IN_PAD * 2, wih_bf, IN_PAD * 2,
                                              b_ih, b_hh, nullptr, xproj, nullptr);
  for (int t = 0; t < T_TICKS; ++t) {
    const bf16* hin = (t & 1) ? hB : hA;
    bf16* hout      = (t & 1) ? hA : hB;
    gemm_bt<HD, 1><<<512, 256, 0, stream>>>(hin, HD * 2, whh_bf, HD * 2,
                                            nullptr, nullptr, xproj, nullptr, hout);
    fe_head<<<B_ROWS / 4, 256, 0, stream>>>(hout, fe_W, fe_b, eps, out, t);
  }
}

// Round 3
// 720.038 us; speedup vs baseline: 2.2447x; 1.3710x over previous
//
#include <hip/hip_runtime.h>
#include <hip/hip_bf16.h>
#include <stdint.h>

#define B_ROWS 4096
#define HD 1024
#define IN_DIM 784
#define IN_PAD 832
#define NEXT 1152          // HD + 128 (fe extension tile)
#define T_TICKS 32

typedef float f32x4 __attribute__((ext_vector_type(4)));
typedef short short8 __attribute__((ext_vector_type(8)));
typedef __hip_bfloat16 bf16;

__device__ __forceinline__ float b2f(short s) {
  unsigned u = ((unsigned)(unsigned short)s) << 16;
  float f; __builtin_memcpy(&f, &u, 4); return f;
}

__device__ __forceinline__ float softplus_f(float x) {
  if (x > 20.f) return x;
  return log1pf(expf(x));
}

__device__ __forceinline__ float tanh_fast(float x) {
  x = fminf(fmaxf(x, -15.f), 15.f);
  float e = __expf(2.f * x);
  return (e - 1.f) / (e + 1.f);
}

__device__ __forceinline__ void gload_lds16(const void* g, void* l) {
  __builtin_amdgcn_global_load_lds(
      (const __attribute__((address_space(1))) uint32_t*)g,
      (__attribute__((address_space(3))) uint32_t*)l, 16, 0, 0);
}

// ---------- f32 -> bf16 with zero-pad of inner dim ----------
__global__ __launch_bounds__(256) void conv_pad_kernel(
    const float* __restrict__ src, bf16* __restrict__ dst,
    int rows, int scols, int dcols) {
  int idx = blockIdx.x * 256 + threadIdx.x;
  int total = rows * dcols;
  if (idx >= total) return;
  int r = idx / dcols, c = idx - r * dcols;
  float v = (c < scols) ? src[(size_t)r * scols + c] : 0.f;
  dst[idx] = __float2bfloat16(v);
}

// ---------- build [W_hh ; fe_W ; 0] (NEXT x HD) bf16 ----------
__global__ __launch_bounds__(256) void build_whhext(
    const float* __restrict__ Whh, const float* __restrict__ feW,
    bf16* __restrict__ dst) {
  int idx = blockIdx.x * 256 + threadIdx.x;
  if (idx >= NEXT * HD) return;
  int r = idx / HD, c = idx - r * HD;
  float v = 0.f;
  if (r < HD) v = Whh[(size_t)r * HD + c];
  else if (r < HD + 5) v = feW[(size_t)(r - HD) * HD + c];
  dst[idx] = __float2bfloat16(v);
}

// ---------- GEMM C = A * B^T ----------
// BM=64, BN=128, BK=64, 256 threads (4 waves 2x2, wave tile 32x64).
// Double-buffered LDS, counted-vmcnt pipeline (no full drain in main loop),
// XOR-swizzled LDS via pre-swizzled global source (rule 21 both-sides).
// MODE 0 (NT=8): xp_out[row][col] = bf16(acc + bias1[col] + bias2[col])
// MODE 1 (NT=9): ny<8 : outH = bf16(tanh(acc + xp[row][col]))
//                ny==8: feRaw[row][tprev][cF] = acc   (cF<5, tprev>=0)
template<int KDIM, int MODE, int NT>
__global__ __launch_bounds__(256) void gemm_bt(
    const bf16* __restrict__ A, int ldaB,
    const bf16* __restrict__ Bw, int ldbB,
    const float* __restrict__ bias1, const float* __restrict__ bias2,
    const bf16* __restrict__ xp, bf16* __restrict__ xp_out,
    bf16* __restrict__ outH, float* __restrict__ feRaw, int tprev)
{
  __shared__ bf16 lA[2][64 * 64];    // 2 x 8KB
  __shared__ bf16 lB[2][128 * 64];   // 2 x 16KB
  const int tid = threadIdx.x;
  const int lane = tid & 63, w = tid >> 6;
  const int wm = w & 1, wn = w >> 1;
  const int l3 = lane >> 3, l7 = lane & 7;
  const int gcol = l7 ^ l3;               // inverse-swizzled source chunk
  const int r = lane & 15, q = lane >> 4;
  const int r7 = r & 7;

  // XCD-chunked bijective swizzle (nwg % 8 == 0 in both modes)
  int bid = blockIdx.x;
  int mx, ny;
  if (NT == 8) {        // nwg = 512, 64 per XCD
    int v = (bid & 7) * 64 + (bid >> 3);
    mx = v >> 3; ny = v & 7;
  } else {              // NT == 9, nwg = 576, 72 per XCD
    int v = (bid & 7) * 72 + (bid >> 3);
    mx = v / 9; ny = v - mx * 9;
  }
  const int bm0 = mx * 64, bn0 = ny * 128;

  f32x4 acc[2][4] = {};

  const char* Asrc = (const char*)A + (size_t)(bm0 + l3) * ldaB + gcol * 16;
  const char* Bsrc = (const char*)Bw + (size_t)(bn0 + l3) * ldbB + gcol * 16;
  char* lAb0 = (char*)&lA[0][0];
  char* lBb0 = (char*)&lB[0][0];

  const int NK = KDIM / 64;

#define STAGE(buf, kt)                                                         \
  {                                                                            \
    const char* Ak = Asrc + (kt) * 128;                                        \
    const char* Bk = Bsrc + (kt) * 128;                                        \
    _Pragma("unroll") for (int j = 0; j < 2; ++j) {                            \
      int iA = w * 2 + j;                                                      \
      gload_lds16(Ak + (size_t)iA * 8 * ldaB, lAb0 + (buf) * 8192 + iA * 1024);\
    }                                                                          \
    _Pragma("unroll") for (int j = 0; j < 4; ++j) {                            \
      int iB = w * 4 + j;                                                      \
      gload_lds16(Bk + (size_t)iB * 8 * ldbB, lBb0 + (buf) * 16384 + iB * 1024);\
    }                                                                          \
  }

  STAGE(0, 0);
  int cur = 0;

  for (int kt = 0; kt < NK; ++kt) {
    if (kt + 1 < NK) {
      STAGE(cur ^ 1, kt + 1);
      // wait for PREVIOUS stage (buf cur) only; 6 newest (cur^1) stay in flight
      asm volatile("s_waitcnt vmcnt(6)" ::: "memory");
    } else {
      asm volatile("s_waitcnt vmcnt(0)" ::: "memory");
    }
    __builtin_amdgcn_s_barrier();          // buf[cur] ready for all waves

    const char* lAb = lAb0 + cur * 8192;
    const char* lBb = lBb0 + cur * 16384;
    short8 af[2][2], bfr[2][4];
#pragma unroll
    for (int ks = 0; ks < 2; ++ks) {
      int cc = ks * 4 + q;
      int sw = (cc ^ r7) << 4;
#pragma unroll
      for (int m = 0; m < 2; ++m) {
        int row = wm * 32 + m * 16 + r;
        af[ks][m] = *(const short8*)(lAb + row * 128 + sw);
      }
#pragma unroll
      for (int n = 0; n < 4; ++n) {
        int row = wn * 64 + n * 16 + r;
        bfr[ks][n] = *(const short8*)(lBb + row * 128 + sw);
      }
    }
    asm volatile("s_waitcnt lgkmcnt(0)" ::: "memory");
    __builtin_amdgcn_s_barrier();          // all waves done reading buf[cur]
    __builtin_amdgcn_sched_barrier(0);     // rule 18: keep MFMA below the wait

#pragma unroll
    for (int ks = 0; ks < 2; ++ks)
#pragma unroll
      for (int m = 0; m < 2; ++m)
#pragma unroll
        for (int n = 0; n < 4; ++n)
          acc[m][n] = __builtin_amdgcn_mfma_f32_16x16x32_bf16(af[ks][m], bfr[ks][n], acc[m][n], 0, 0, 0);

    cur ^= 1;
  }
#undef STAGE

#pragma unroll
  for (int m = 0; m < 2; ++m) {
#pragma unroll
    for (int n = 0; n < 4; ++n) {
      int coll = wn * 64 + n * 16 + r;
      int col = bn0 + coll;
#pragma unroll
      for (int i = 0; i < 4; ++i) {
        int row = bm0 + wm * 32 + m * 16 + q * 4 + i;
        float v = acc[m][n][i];
        if (MODE == 0) {
          xp_out[(size_t)row * HD + col] = __float2bfloat16(v + bias1[col] + bias2[col]);
        } else {
          if (NT == 9 && ny == 8) {
            if (coll < 5 && tprev >= 0)
              feRaw[((size_t)row * T_TICKS + tprev) * 5 + coll] = v;
          } else {
            float val = tanh_fast(v + b2f(*(const short*)&xp[(size_t)row * HD + col]));
            outH[(size_t)row * HD + col] = __float2bfloat16(val);
          }
        }
      }
    }
  }
}

// ---------- fe for the last tick: one wave per row, 5 raw dots ----------
__global__ __launch_bounds__(256) void fe_last(
    const bf16* __restrict__ h, const float* __restrict__ feW,
    float* __restrict__ feRaw)
{
  int wid = threadIdx.x >> 6, lane = threadIdx.x & 63;
  int b = blockIdx.x * 4 + wid;
  const bf16* hr = h + (size_t)b * HD + lane * 16;
  short8 hv0 = *(const short8*)hr;
  short8 hv1 = *(const short8*)(hr + 8);
  float hvf[16];
#pragma unroll
  for (int e = 0; e < 8; ++e) { hvf[e] = b2f(hv0[e]); hvf[8 + e] = b2f(hv1[e]); }

  float a0 = 0, a1 = 0, a2 = 0, a3 = 0, a4 = 0;
  int col0 = lane * 16;
#pragma unroll
  for (int e = 0; e < 16; ++e) {
    float hv = hvf[e];
    int col = col0 + e;
    a0 += hv * feW[0 * HD + col];
    a1 += hv * feW[1 * HD + col];
    a2 += hv * feW[2 * HD + col];
    a3 += hv * feW[3 * HD + col];
    a4 += hv * feW[4 * HD + col];
  }
#pragma unroll
  for (int off = 32; off >= 1; off >>= 1) {
    a0 += __shfl_xor(a0, off);
    a1 += __shfl_xor(a1, off);
    a2 += __shfl_xor(a2, off);
    a3 += __shfl_xor(a3, off);
    a4 += __shfl_xor(a4, off);
  }
  if (lane == 0) {
    float* fr = feRaw + ((size_t)b * T_TICKS + (T_TICKS - 1)) * 5;
    fr[0] = a0; fr[1] = a1; fr[2] = a2; fr[3] = a3; fr[4] = a4;
  }
}

// ---------- finish: softplus / z / L for all (b,t) ----------
__global__ __launch_bounds__(256) void finish_kernel(
    const float* __restrict__ feRaw, const float* __restrict__ feB,
    const float* __restrict__ eps, float* __restrict__ out)
{
  int gid = blockIdx.x * 256 + threadIdx.x;
  if (gid >= B_ROWS * T_TICKS) return;
  int b = gid >> 5, t = gid & 31;
  const float* fr = feRaw + ((size_t)b * T_TICKS + t) * 5;
  float mu0 = fr[0] + feB[0], mu1 = fr[1] + feB[1];
  float L00 = softplus_f(fr[2] + feB[2]);
  float L10 = fr[3] + feB[3];
  float L11 = softplus_f(fr[4] + feB[4]);
  const float* ep = eps + ((size_t)t * B_ROWS + b) * 2;
  float e0 = ep[0], e1 = ep[1];
  float z0 = mu0 + L00 * e0;
  float z1 = mu1 + L10 * e0 + L11 * e1;

  float* zs0 = out;
  float* zs1 = out + (size_t)B_ROWS * 2 * T_TICKS;
  float* Ls  = out + (size_t)2 * B_ROWS * 2 * T_TICKS;
  size_t zb = (size_t)b * 2 * T_TICKS + t;
  zs0[zb] = z0; zs0[zb + T_TICKS] = z1;
  zs1[zb] = z0; zs1[zb + T_TICKS] = z1;
  size_t lb = (size_t)b * 4 * T_TICKS + t;
  Ls[lb] = L00;
  Ls[lb + T_TICKS] = 0.f;
  Ls[lb + 2 * T_TICKS] = L10;
  Ls[lb + 3 * T_TICKS] = L11;
}

extern "C" void kernel_launch(void* const* d_in, const int* in_sizes, int n_in,
                              void* d_out, int out_size, void* d_ws, size_t ws_size,
                              hipStream_t stream) {
  const float* x    = (const float*)d_in[0];
  const float* hx   = (const float*)d_in[1];
  const float* eps  = (const float*)d_in[2];
  const float* W_ih = (const float*)d_in[3];
  const float* b_ih = (const float*)d_in[4];
  const float* W_hh = (const float*)d_in[5];
  const float* b_hh = (const float*)d_in[6];
  const float* fe_W = (const float*)d_in[7];
  const float* fe_b = (const float*)d_in[8];
  float* out = (float*)d_out;

  char* ws = (char*)d_ws;
  bf16* x_bf    = (bf16*)ws;  ws += (size_t)B_ROWS * IN_PAD * 2;
  bf16* wih_bf  = (bf16*)ws;  ws += (size_t)HD * IN_PAD * 2;
  bf16* whhe_bf = (bf16*)ws;  ws += (size_t)NEXT * HD * 2;
  bf16* xp_bf   = (bf16*)ws;  ws += (size_t)B_ROWS * HD * 2;
  bf16* hA = (bf16*)ws;       ws += (size_t)B_ROWS * HD * 2;
  bf16* hB = (bf16*)ws;       ws += (size_t)B_ROWS * HD * 2;
  float* feRaw = (float*)ws;  ws += (size_t)B_ROWS * T_TICKS * 5 * 4;

  conv_pad_kernel<<<(B_ROWS * IN_PAD + 255) / 256, 256, 0, stream>>>(x, x_bf, B_ROWS, IN_DIM, IN_PAD);
  conv_pad_kernel<<<(HD * IN_PAD + 255) / 256, 256, 0, stream>>>(W_ih, wih_bf, HD, IN_DIM, IN_PAD);
  build_whhext<<<(NEXT * HD + 255) / 256, 256, 0, stream>>>(W_hh, fe_W, whhe_bf);
  conv_pad_kernel<<<(B_ROWS * HD + 255) / 256, 256, 0, stream>>>(hx, hA, B_ROWS, HD, HD);

  // x_proj (+ both biases) -> bf16 : grid 64 x 8 = 512
  gemm_bt<IN_PAD, 0, 8><<<512, 256, 0, stream>>>(
      x_bf, IN_PAD * 2, wih_bf, IN_PAD * 2, b_ih, b_hh,
      nullptr, xp_bf, nullptr, nullptr, -1);

  // ticks: grid 64 x 9 = 576 (N = 1024 h-cols + 128 fe-ext cols)
  for (int t = 0; t < T_TICKS; ++t) {
    const bf16* hin = (t & 1) ? hB : hA;
    bf16* hout      = (t & 1) ? hA : hB;
    gemm_bt<HD, 1, 9><<<576, 256, 0, stream>>>(
        hin, HD * 2, whhe_bf, HD * 2, nullptr, nullptr,
        xp_bf, nullptr, hout, feRaw, t - 1);
  }
  // final h is in hA (t=31 odd -> hout = hA)
  fe_last<<<B_ROWS / 4, 256, 0, stream>>>(hA, fe_W, feRaw);
  finish_kernel<<<(B_ROWS * T_TICKS + 255) / 256, 256, 0, stream>>>(feRaw, fe_b, eps, out);
}

// Round 4
// 576.819 us; speedup vs baseline: 2.8021x; 1.2483x over previous
//
#include <hip/hip_runtime.h>
#include <hip/hip_bf16.h>
#include <stdint.h>

#define B_ROWS 4096
#define HD 1024
#define IN_DIM 784
#define IN_PAD 832
#define T_TICKS 32

typedef float f32x4 __attribute__((ext_vector_type(4)));
typedef short short8 __attribute__((ext_vector_type(8)));
typedef __hip_bfloat16 bf16;

#define BUF_SZ 24576              // A 8KB + B 16KB per buffer
#define FEW_OFF (3 * BUF_SZ)      // feW buffers after the 3 main buffers
#define LDS_TOTAL (3 * BUF_SZ + 3 * 2048)

__device__ __forceinline__ float b2f(short s) {
  unsigned u = ((unsigned)(unsigned short)s) << 16;
  float f; __builtin_memcpy(&f, &u, 4); return f;
}

__device__ __forceinline__ float softplus_f(float x) {
  if (x > 20.f) return x;
  return log1pf(expf(x));
}

__device__ __forceinline__ float tanh_fast(float x) {
  x = fminf(fmaxf(x, -15.f), 15.f);
  float e = __expf(2.f * x);
  return (e - 1.f) / (e + 1.f);
}

__device__ __forceinline__ void gload_lds16(const void* g, void* l) {
  __builtin_amdgcn_global_load_lds(
      (const __attribute__((address_space(1))) uint32_t*)g,
      (__attribute__((address_space(3))) uint32_t*)l, 16, 0, 0);
}

// ---------- f32 -> bf16 with zero-pad of inner dim ----------
__global__ __launch_bounds__(256) void conv_pad_kernel(
    const float* __restrict__ src, bf16* __restrict__ dst,
    int rows, int scols, int dcols) {
  int idx = blockIdx.x * 256 + threadIdx.x;
  int total = rows * dcols;
  if (idx >= total) return;
  int r = idx / dcols, c = idx - r * dcols;
  float v = (c < scols) ? src[(size_t)r * scols + c] : 0.f;
  dst[idx] = __float2bfloat16(v);
}

// ---------- build whh_bf (1024x1024) and feWp (16x1024, rows 5..15 zero) ----------
__global__ __launch_bounds__(256) void build_wext(
    const float* __restrict__ Whh, const float* __restrict__ feW,
    bf16* __restrict__ whh_bf, bf16* __restrict__ feWp) {
  int idx = blockIdx.x * 256 + threadIdx.x;
  if (idx >= (HD + 16) * HD) return;
  int r = idx / HD, c = idx - r * HD;
  if (r < HD) {
    whh_bf[idx] = __float2bfloat16(Whh[(size_t)r * HD + c]);
  } else {
    int fr = r - HD;
    float v = (fr < 5) ? feW[(size_t)fr * HD + c] : 0.f;
    feWp[(size_t)fr * HD + c] = __float2bfloat16(v);
  }
}

// ---------- GEMM C = A * B^T ----------
// BM=64, BN=128, BK=64, 256 threads (4 waves 2x2, wave tile 32x64).
// 3 LDS buffers, depth-2 counted-vmcnt pipeline, XOR-swizzled LDS via
// pre-swizzled global source. Grid 512 = 2 blocks/CU exactly.
// MODE 0: xp_out = bf16(acc + bias1 + bias2)
// MODE 1: outH = bf16(tanh(acc + xp)); fe side-compute on wave0 of ny<4 blocks:
//         feRaw[row][tprev][c<5] = (A-rows [ny*16,+16)) . feWp  via 2 extra MFMA/iter
template<int KDIM, int MODE>
__global__ __launch_bounds__(256) void gemm_bt(
    const bf16* __restrict__ A,
    const bf16* __restrict__ Bw,
    const bf16* __restrict__ feWp,
    const float* __restrict__ bias1, const float* __restrict__ bias2,
    const bf16* __restrict__ xp, bf16* __restrict__ xp_out,
    bf16* __restrict__ outH, float* __restrict__ feRaw, int tprev)
{
  __shared__ char lds[LDS_TOTAL];
  const int tid = threadIdx.x;
  const int lane = tid & 63, w = tid >> 6;
  const int wm = w & 1, wn = w >> 1;
  const int l3 = lane >> 3, l7 = lane & 7;
  const int gcol = l7 ^ l3;               // inverse-swizzled source chunk
  const int r = lane & 15, q = lane >> 4;
  const int r7 = r & 7;
  const int ldaB = KDIM * 2, ldbB = KDIM * 2;

  // XCD-chunked bijective swizzle: nwg = 512, 64 per XCD
  int bid = blockIdx.x;
  int v = (bid & 7) * 64 + (bid >> 3);
  const int mx = v >> 3, ny = v & 7;
  const int bm0 = mx * 64, bn0 = ny * 128;

  const bool feB = (MODE == 1) && (ny < 4);
  const bool feW0 = feB && (w == 0);

  f32x4 acc[2][4] = {};
  f32x4 acc_fe = {};

  const char* Asrc = (const char*)A + (size_t)(bm0 + l3) * ldaB + gcol * 16;
  const char* Bsrc = (const char*)Bw + (size_t)(bn0 + l3) * ldbB + gcol * 16;
  const char* Fsrc = (const char*)feWp + (size_t)l3 * 2048 + gcol * 16;

  const int NK = KDIM / 64;

#define STAGE(buf, kt)                                                          \
  {                                                                             \
    const char* Ak = Asrc + (kt) * 128;                                         \
    const char* Bk = Bsrc + (kt) * 128;                                         \
    _Pragma("unroll") for (int j = 0; j < 2; ++j) {                             \
      int iA = w * 2 + j;                                                       \
      gload_lds16(Ak + (size_t)iA * 8 * ldaB, lds + (buf) * BUF_SZ + iA * 1024);\
    }                                                                           \
    _Pragma("unroll") for (int j = 0; j < 4; ++j) {                             \
      int iB = w * 4 + j;                                                       \
      gload_lds16(Bk + (size_t)iB * 8 * ldbB,                                   \
                  lds + (buf) * BUF_SZ + 8192 + iB * 1024);                     \
    }                                                                           \
    if (feW0) {                                                                 \
      const char* Fk = Fsrc + (kt) * 128;                                       \
      _Pragma("unroll") for (int j = 0; j < 2; ++j) {                           \
        gload_lds16(Fk + (size_t)j * 8 * 2048,                                  \
                    lds + FEW_OFF + (buf) * 2048 + j * 1024);                   \
      }                                                                         \
    }                                                                           \
  }

  STAGE(0, 0);
  STAGE(1, 1);
  int b0 = 0;   // buffer holding tile kt

  for (int kt = 0; kt < NK; ++kt) {
    int bs = b0 + 2; if (bs >= 3) bs -= 3;
    if (kt + 2 < NK) {
      STAGE(bs, kt + 2);
      if (feW0) asm volatile("s_waitcnt vmcnt(16)" ::: "memory");
      else      asm volatile("s_waitcnt vmcnt(12)" ::: "memory");
    } else if (kt + 2 == NK) {
      if (feW0) asm volatile("s_waitcnt vmcnt(8)" ::: "memory");
      else      asm volatile("s_waitcnt vmcnt(6)" ::: "memory");
    } else {
      asm volatile("s_waitcnt vmcnt(0)" ::: "memory");
    }
    __builtin_amdgcn_s_barrier();          // buf[b0] fully staged
    __builtin_amdgcn_sched_barrier(0);

    const char* lAb = lds + b0 * BUF_SZ;
    const char* lBb = lAb + 8192;
    short8 af[2][2], bfr[2][4], af_fe[2], bf_fe[2];
#pragma unroll
    for (int ks = 0; ks < 2; ++ks) {
      int cc = ks * 4 + q;
      int sw = (cc ^ r7) << 4;
#pragma unroll
      for (int m = 0; m < 2; ++m) {
        int row = wm * 32 + m * 16 + r;
        af[ks][m] = *(const short8*)(lAb + row * 128 + sw);
      }
#pragma unroll
      for (int n = 0; n < 4; ++n) {
        int row = wn * 64 + n * 16 + r;
        bfr[ks][n] = *(const short8*)(lBb + row * 128 + sw);
      }
    }
    if (feW0) {
      const char* lFb = lds + FEW_OFF + b0 * 2048;
#pragma unroll
      for (int ks = 0; ks < 2; ++ks) {
        int sw = ((ks * 4 + q) ^ r7) << 4;
        af_fe[ks] = *(const short8*)(lAb + (ny * 16 + r) * 128 + sw);
        bf_fe[ks] = *(const short8*)(lFb + r * 128 + sw);
      }
    }
    asm volatile("s_waitcnt lgkmcnt(0)" ::: "memory");
    __builtin_amdgcn_s_barrier();          // all waves done reading buf[b0]
    __builtin_amdgcn_sched_barrier(0);     // rule 18: keep MFMA below the wait

#pragma unroll
    for (int ks = 0; ks < 2; ++ks)
#pragma unroll
      for (int m = 0; m < 2; ++m)
#pragma unroll
        for (int n = 0; n < 4; ++n)
          acc[m][n] = __builtin_amdgcn_mfma_f32_16x16x32_bf16(af[ks][m], bfr[ks][n], acc[m][n], 0, 0, 0);
    if (feW0) {
      acc_fe = __builtin_amdgcn_mfma_f32_16x16x32_bf16(af_fe[0], bf_fe[0], acc_fe, 0, 0, 0);
      acc_fe = __builtin_amdgcn_mfma_f32_16x16x32_bf16(af_fe[1], bf_fe[1], acc_fe, 0, 0, 0);
    }

    if (++b0 == 3) b0 = 0;
  }
#undef STAGE

#pragma unroll
  for (int m = 0; m < 2; ++m) {
#pragma unroll
    for (int n = 0; n < 4; ++n) {
      int col = bn0 + wn * 64 + n * 16 + r;
#pragma unroll
      for (int i = 0; i < 4; ++i) {
        int row = bm0 + wm * 32 + m * 16 + q * 4 + i;
        float vv = acc[m][n][i];
        if (MODE == 0) {
          xp_out[(size_t)row * HD + col] = __float2bfloat16(vv + bias1[col] + bias2[col]);
        } else {
          float val = tanh_fast(vv + b2f(*(const short*)&xp[(size_t)row * HD + col]));
          outH[(size_t)row * HD + col] = __float2bfloat16(val);
        }
      }
    }
  }
  if (MODE == 1 && feW0 && tprev >= 0 && r < 5) {
#pragma unroll
    for (int i = 0; i < 4; ++i) {
      int rowg = bm0 + ny * 16 + q * 4 + i;
      feRaw[((size_t)rowg * T_TICKS + tprev) * 5 + r] = acc_fe[i];
    }
  }
}

// ---------- fe for the last tick: one wave per row, 5 raw dots ----------
__global__ __launch_bounds__(256) void fe_last(
    const bf16* __restrict__ h, const float* __restrict__ feW,
    float* __restrict__ feRaw)
{
  int wid = threadIdx.x >> 6, lane = threadIdx.x & 63;
  int b = blockIdx.x * 4 + wid;
  const bf16* hr = h + (size_t)b * HD + lane * 16;
  short8 hv0 = *(const short8*)hr;
  short8 hv1 = *(const short8*)(hr + 8);
  float hvf[16];
#pragma unroll
  for (int e = 0; e < 8; ++e) { hvf[e] = b2f(hv0[e]); hvf[8 + e] = b2f(hv1[e]); }

  float a0 = 0, a1 = 0, a2 = 0, a3 = 0, a4 = 0;
  int col0 = lane * 16;
#pragma unroll
  for (int e = 0; e < 16; ++e) {
    float hv = hvf[e];
    int col = col0 + e;
    a0 += hv * feW[0 * HD + col];
    a1 += hv * feW[1 * HD + col];
    a2 += hv * feW[2 * HD + col];
    a3 += hv * feW[3 * HD + col];
    a4 += hv * feW[4 * HD + col];
  }
#pragma unroll
  for (int off = 32; off >= 1; off >>= 1) {
    a0 += __shfl_xor(a0, off);
    a1 += __shfl_xor(a1, off);
    a2 += __shfl_xor(a2, off);
    a3 += __shfl_xor(a3, off);
    a4 += __shfl_xor(a4, off);
  }
  if (lane == 0) {
    float* fr = feRaw + ((size_t)b * T_TICKS + (T_TICKS - 1)) * 5;
    fr[0] = a0; fr[1] = a1; fr[2] = a2; fr[3] = a3; fr[4] = a4;
  }
}

// ---------- finish: softplus / z / L for all (b,t) ----------
__global__ __launch_bounds__(256) void finish_kernel(
    const float* __restrict__ feRaw, const float* __restrict__ feB,
    const float* __restrict__ eps, float* __restrict__ out)
{
  int gid = blockIdx.x * 256 + threadIdx.x;
  if (gid >= B_ROWS * T_TICKS) return;
  int b = gid >> 5, t = gid & 31;
  const float* fr = feRaw + ((size_t)b * T_TICKS + t) * 5;
  float mu0 = fr[0] + feB[0], mu1 = fr[1] + feB[1];
  float L00 = softplus_f(fr[2] + feB[2]);
  float L10 = fr[3] + feB[3];
  float L11 = softplus_f(fr[4] + feB[4]);
  const float* ep = eps + ((size_t)t * B_ROWS + b) * 2;
  float e0 = ep[0], e1 = ep[1];
  float z0 = mu0 + L00 * e0;
  float z1 = mu1 + L10 * e0 + L11 * e1;

  float* zs0 = out;
  float* zs1 = out + (size_t)B_ROWS * 2 * T_TICKS;
  float* Ls  = out + (size_t)2 * B_ROWS * 2 * T_TICKS;
  size_t zb = (size_t)b * 2 * T_TICKS + t;
  zs0[zb] = z0; zs0[zb + T_TICKS] = z1;
  zs1[zb] = z0; zs1[zb + T_TICKS] = z1;
  size_t lb = (size_t)b * 4 * T_TICKS + t;
  Ls[lb] = L00;
  Ls[lb + T_TICKS] = 0.f;
  Ls[lb + 2 * T_TICKS] = L10;
  Ls[lb + 3 * T_TICKS] = L11;
}

extern "C" void kernel_launch(void* const* d_in, const int* in_sizes, int n_in,
                              void* d_out, int out_size, void* d_ws, size_t ws_size,
                              hipStream_t stream) {
  const float* x    = (const float*)d_in[0];
  const float* hx   = (const float*)d_in[1];
  const float* eps  = (const float*)d_in[2];
  const float* W_ih = (const float*)d_in[3];
  const float* b_ih = (const float*)d_in[4];
  const float* W_hh = (const float*)d_in[5];
  const float* b_hh = (const float*)d_in[6];
  const float* fe_W = (const float*)d_in[7];
  const float* fe_b = (const float*)d_in[8];
  float* out = (float*)d_out;

  char* ws = (char*)d_ws;
  bf16* x_bf    = (bf16*)ws;  ws += (size_t)B_ROWS * IN_PAD * 2;
  bf16* wih_bf  = (bf16*)ws;  ws += (size_t)HD * IN_PAD * 2;
  bf16* whh_bf  = (bf16*)ws;  ws += (size_t)HD * HD * 2;
  bf16* feWp    = (bf16*)ws;  ws += (size_t)16 * HD * 2;
  bf16* xp_bf   = (bf16*)ws;  ws += (size_t)B_ROWS * HD * 2;
  bf16* hA = (bf16*)ws;       ws += (size_t)B_ROWS * HD * 2;
  bf16* hB = (bf16*)ws;       ws += (size_t)B_ROWS * HD * 2;
  float* feRaw = (float*)ws;  ws += (size_t)B_ROWS * T_TICKS * 5 * 4;

  conv_pad_kernel<<<(B_ROWS * IN_PAD + 255) / 256, 256, 0, stream>>>(x, x_bf, B_ROWS, IN_DIM, IN_PAD);
  conv_pad_kernel<<<(HD * IN_PAD + 255) / 256, 256, 0, stream>>>(W_ih, wih_bf, HD, IN_DIM, IN_PAD);
  build_wext<<<((HD + 16) * HD + 255) / 256, 256, 0, stream>>>(W_hh, fe_W, whh_bf, feWp);
  conv_pad_kernel<<<(B_ROWS * HD + 255) / 256, 256, 0, stream>>>(hx, hA, B_ROWS, HD, HD);

  // x_proj (+ both biases) -> bf16 : grid 512
  gemm_bt<IN_PAD, 0><<<512, 256, 0, stream>>>(
      x_bf, wih_bf, nullptr, b_ih, b_hh,
      nullptr, xp_bf, nullptr, nullptr, -1);

  // ticks: grid 512 (N = 1024), fe for h_{t-1} fused on wave0 of ny<4 blocks
  for (int t = 0; t < T_TICKS; ++t) {
    const bf16* hin = (t & 1) ? hB : hA;
    bf16* hout      = (t & 1) ? hA : hB;
    gemm_bt<HD, 1><<<512, 256, 0, stream>>>(
        hin, whh_bf, feWp, nullptr, nullptr,
        xp_bf, nullptr, hout, feRaw, t - 1);
  }
  // final h is in hA (t=31 odd -> hout = hA)
  fe_last<<<B_ROWS / 4, 256, 0, stream>>>(hA, fe_W, feRaw);
  finish_kernel<<<(B_ROWS * T_TICKS + 255) / 256, 256, 0, stream>>>(feRaw, fe_b, eps, out);
}